// Round 9
// baseline (233.015 us; speedup 1.0000x reference)
//
#include <hip/hip_runtime.h>
#include <hip/hip_bf16.h>
#include <stdint.h>

// B=32768, D=1024, T=8, O=128, DEPTH=6 -> 512 padded node cols (8 trees x 64)
#define KDIM 1024
#define XCH 136            // x chunk row stride (shorts): 272 B == 16 mod 128 (uniform bank slots)
#define TSTR 72            // tree stride in st (shorts)
#define RSTR 584           // st row stride (shorts): 1168 B == 16 mod 128 (uniform bank slots)

typedef __attribute__((ext_vector_type(4))) float f32x4;
typedef __attribute__((ext_vector_type(8))) short bf16x8;

// ws: wb [32 ks][32 cb][64 lane][8] bf16 = 1 MiB @0 ; lb [16 kq][8 obk][64 lane][8] bf16 @1 MiB
#define WS_LB_OFF ((size_t)1 << 20)

__device__ __forceinline__ unsigned short f2bf_rne(float f) {
    unsigned u = __float_as_uint(f);
    u = (u + 0x7fffu + ((u >> 16) & 1u)) >> 16;
    return (unsigned short)u;
}

__device__ __forceinline__ unsigned int pack2_bf16(float a, float b) {
    __hip_bfloat162 h = __float22bfloat162_rn(make_float2(a, b));
    union { __hip_bfloat162 h; unsigned int u; } cv;
    cv.h = h;
    return cv.u;   // a low 16, b high
}

__device__ __forceinline__ float gs_get(const uint4* q, int i) {
    uint4 v = q[i >> 3];
    int c = (i >> 1) & 3;
    unsigned w = (c == 0) ? v.x : (c == 1) ? v.y : (c == 2) ? v.z : v.w;
    return __uint_as_float((i & 1) ? (w & 0xffff0000u) : (w << 16));
}

// ---- merged prep: blocks [0,2048) = node weights, [2048,2304) = leaf weights.
__global__ void prep(const float* __restrict__ nw, const float* __restrict__ lw,
                     unsigned short* __restrict__ wb, unsigned short* __restrict__ lb) {
    int b = blockIdx.x;
    if (b < 2048) {
        int idx = b * 256 + threadIdx.x;            // 524288 total
        int e    = idx & 7;
        int lane = (idx >> 3) & 63;
        int cb   = (idx >> 9) & 31;
        int ks   = idx >> 14;
        int col = cb * 16 + (lane & 15);
        int k   = ks * 32 + (lane >> 4) * 8 + e;
        int t = col >> 6, i = col & 63;
        float v = (i < 63) ? nw[(t * KDIM + k) * 63 + i] : 0.0f;
        wb[idx] = f2bf_rne(v);
    } else {
        int idx = (b - 2048) * 256 + threadIdx.x;   // 65536 total
        int e    = idx & 7;
        int lane = (idx >> 3) & 63;
        int obk  = (idx >> 9) & 7;
        int kq   = idx >> 12;
        int o = obk * 16 + (lane & 15);
        int c = kq * 32 + (lane >> 4) * 8 + e;
        int t = c >> 6, l = c & 63;
        lb[idx] = f2bf_rne(lw[(t * 128 + o) * 64 + l]);
    }
}

// ---- fused: block = 1024 thr (16 waves), tile 64 rows x 512 cols, acc[2][4].
// GEMM1: 8-chunk (k=128) straight-line pipeline: PRE(c+1) [2 f32x4 nt loads,
// 8 VGPR] -> COMPUTE(c) [loads land under it] -> WR(other buf) -> barrier.
// Named A/B buffers, plain __syncthreads only, no runtime buffer indexing.
// W/leaf direct-global fragment-linear (L2-hot). Tail: single 64-row pass.
__launch_bounds__(1024, 4)
__global__ void fused(const float* __restrict__ x, const unsigned short* __restrict__ wb,
                      const unsigned short* __restrict__ lb, float* __restrict__ out) {
    __shared__ union __align__(16) {
        struct { unsigned short A[64 * XCH], B[64 * XCH]; } xs;   // 2 x 17,408 B
        unsigned short st[64 * RSTR];                             // 74,752 B
    } sm;

    const int tid  = threadIdx.x;
    const int wave = tid >> 6, lane = tid & 63;
    const int quad = lane >> 4, l16 = lane & 15;
    const int mb   = blockIdx.x;           // 512 blocks x 64 rows

    f32x4 acc[2][4];                       // [ct][rt]
    const f32x4 z4 = {0.f, 0.f, 0.f, 0.f};
    #pragma unroll
    for (int a = 0; a < 2; ++a)
        #pragma unroll
        for (int b = 0; b < 4; ++b) acc[a][b] = z4;

    const int srow = tid >> 4, sseg = tid & 15;      // staging: row 0..63, 8-float seg 0..15
    const float* xgr = x + (size_t)(mb * 64 + srow) * KDIM + sseg * 8;
    const unsigned short* wb0 = wb + ((size_t)(wave * 2) * 64 + lane) * 8;

    f32x4 p0, p1;                                    // chunk prefetch (8 VGPR)
    auto PRE = [&](int c) {
        p0 = __builtin_nontemporal_load((const f32x4*)(xgr + c * 128));
        p1 = __builtin_nontemporal_load((const f32x4*)(xgr + c * 128 + 4));
    };
    auto WR = [&](unsigned short* buf) {
        uint4 pk;
        pk.x = pack2_bf16(p0[0], p0[1]);
        pk.y = pack2_bf16(p0[2], p0[3]);
        pk.z = pack2_bf16(p1[0], p1[1]);
        pk.w = pack2_bf16(p1[2], p1[3]);
        *(uint4*)&buf[srow * XCH + sseg * 8] = pk;
    };
    auto COMPUTE = [&](const unsigned short* buf, int c) {
        #pragma unroll
        for (int ksl = 0; ksl < 4; ++ksl) {
            bf16x8 bf[4], af[2];
            #pragma unroll
            for (int rt = 0; rt < 4; ++rt)
                bf[rt] = *(const bf16x8*)&buf[(rt * 16 + l16) * XCH + ksl * 32 + quad * 8];
            const unsigned short* wbase = wb0 + (size_t)(c * 4 + ksl) * 16384;
            af[0] = *(const bf16x8*)(wbase);
            af[1] = *(const bf16x8*)(wbase + 512);
            #pragma unroll
            for (int ct = 0; ct < 2; ++ct)
                #pragma unroll
                for (int rt = 0; rt < 4; ++rt)
                    acc[ct][rt] = __builtin_amdgcn_mfma_f32_16x16x32_bf16(af[ct], bf[rt], acc[ct][rt], 0, 0, 0);
        }
    };

    PRE(0); WR(sm.xs.A); __syncthreads();
    PRE(1); COMPUTE(sm.xs.A, 0); WR(sm.xs.B); __syncthreads();
    PRE(2); COMPUTE(sm.xs.B, 1); WR(sm.xs.A); __syncthreads();
    PRE(3); COMPUTE(sm.xs.A, 2); WR(sm.xs.B); __syncthreads();
    PRE(4); COMPUTE(sm.xs.B, 3); WR(sm.xs.A); __syncthreads();
    PRE(5); COMPUTE(sm.xs.A, 4); WR(sm.xs.B); __syncthreads();
    PRE(6); COMPUTE(sm.xs.B, 5); WR(sm.xs.A); __syncthreads();
    PRE(7); COMPUTE(sm.xs.A, 6); WR(sm.xs.B); __syncthreads();
    COMPUTE(sm.xs.B, 7);

    __syncthreads();                       // all xs reads done -> st may alias
    // epilogue: smooth_step, all 64 rows -> st (tree-strided layout)
    #pragma unroll
    for (int rt = 0; rt < 4; ++rt) {
        int r = rt * 16 + l16;             // row 0..63
        #pragma unroll
        for (int ct = 0; ct < 2; ++ct) {
            int colb = wave * 32 + ct * 16 + quad * 4;     // node col 0..511
            f32x4 a = acc[ct][rt];
            float s0[4];
            #pragma unroll
            for (int j = 0; j < 4; ++j) {
                float u = a[j];
                u = fminf(fmaxf(u, -0.5f), 0.5f);          // cubic(+-.5) = 1/0 exactly
                s0[j] = u * (1.5f - 2.0f * u * u) + 0.5f;
            }
            uint2 pk;
            pk.x = pack2_bf16(s0[0], s0[1]);
            pk.y = pack2_bf16(s0[2], s0[3]);
            *(uint2*)&sm.st[r * RSTR + (colb >> 6) * TSTR + (colb & 63)] = pk;
        }
    }
    __syncthreads();
    // scan: one (row, tree) per thread, 512 tasks, in place s -> mu
    if (tid < 512) {
        int r = tid >> 3, t = tid & 7;
        unsigned short* base = &sm.st[r * RSTR + t * TSTR];
        uint4 q[8];
        #pragma unroll
        for (int c = 0; c < 8; ++c) q[c] = *(const uint4*)(base + c * 8);
        float mu[32];
        mu[0] = 1.0f;
        int start = 0;
        #pragma unroll
        for (int lvl = 0; lvl < 5; ++lvl) {
            int width = 1 << lvl;
            #pragma unroll
            for (int j = width - 1; j >= 0; --j) {
                float m = mu[j], s_ = gs_get(q, start + j);
                mu[2 * j + 1] = m * (1.0f - s_);
                mu[2 * j]     = m * s_;
            }
            start += width;
        }
        #pragma unroll
        for (int c = 0; c < 8; ++c) {
            unsigned pk2[4];
            #pragma unroll
            for (int e = 0; e < 4; ++e) {
                int j = c * 4 + e;
                float m = mu[j], s_ = gs_get(q, 31 + j);
                pk2[e] = pack2_bf16(m * s_, m * (1.0f - s_));
            }
            uint4 v; v.x = pk2[0]; v.y = pk2[1]; v.z = pk2[2]; v.w = pk2[3];
            *(uint4*)(base + c * 8) = v;
        }
    }
    __syncthreads();
    // GEMM2: A = leaf (global fragment-linear, L2-hot), B = mu (st)
    {
        int rtile = wave & 3, obk2 = wave >> 2;
        int mr = rtile * 16 + l16;         // row 0..63
        f32x4 a2[2];
        a2[0] = z4; a2[1] = z4;
        #pragma unroll
        for (int kq = 0; kq < 16; ++kq) {
            int c0 = kq * 32 + quad * 8;
            bf16x8 bmu = *(const bf16x8*)&sm.st[mr * RSTR + (c0 >> 6) * TSTR + (c0 & 63)];
            #pragma unroll
            for (int i = 0; i < 2; ++i) {
                int obk = obk2 * 2 + i;
                bf16x8 alf = *(const bf16x8*)(lb + ((size_t)((kq * 8 + obk) * 64 + lane)) * 8);
                a2[i] = __builtin_amdgcn_mfma_f32_16x16x32_bf16(alf, bmu, a2[i], 0, 0, 0);
            }
        }
        int rowg = mb * 64 + rtile * 16 + l16;
        #pragma unroll
        for (int i = 0; i < 2; ++i) {
            int og = (obk2 * 2 + i) * 16 + quad * 4;
            __builtin_nontemporal_store(a2[i], (f32x4*)(out + (size_t)rowg * 128 + og));
        }
    }
}

extern "C" void kernel_launch(void* const* d_in, const int* in_sizes, int n_in,
                              void* d_out, int out_size, void* d_ws, size_t ws_size,
                              hipStream_t stream) {
    const float* x  = (const float*)d_in[0];
    const float* nw = (const float*)d_in[1];
    const float* lw = (const float*)d_in[2];
    float* out = (float*)d_out;

    unsigned short* wb = (unsigned short*)d_ws;
    unsigned short* lb = (unsigned short*)((char*)d_ws + WS_LB_OFF);

    prep<<<2304, 256, 0, stream>>>(nw, lw, wb, lb);
    fused<<<512, 1024, 0, stream>>>(x, wb, lb, out);
}